// Round 10
// baseline (168.351 us; speedup 1.0000x reference)
//
#include <hip/hip_runtime.h>

typedef __bf16 bf16x8 __attribute__((ext_vector_type(8)));
typedef float f32x4 __attribute__((ext_vector_type(4)));
typedef unsigned short u16;
typedef unsigned int u32;
typedef u32 u32x4 __attribute__((ext_vector_type(4)));
typedef u32 u32x2 __attribute__((ext_vector_type(2)));
typedef u16 u16x8 __attribute__((ext_vector_type(8)));

#define B_ 2
#define T_ 2048
#define C_ 1024
#define H_ 16
#define D_ 64
// 0.125 * log2(e): folded into Q so attn softmax runs in exp2 domain
#define QSCALE 0.18033688011112042f

__device__ __forceinline__ u16 f2bf(float f) {
    u32 u = __builtin_bit_cast(u32, f);
    u += 0x7fffu + ((u >> 16) & 1u);
    return (u16)(u >> 16);
}

__device__ __forceinline__ f32x4 mfma16(bf16x8 a, bf16x8 b, f32x4 c) {
    return __builtin_amdgcn_mfma_f32_16x16x32_bf16(a, b, c, 0, 0, 0);
}

// async global->LDS, 16B per lane; LDS dest = wave-uniform base + lane*16
__device__ __forceinline__ void gll16(const u16* g, u16* l) {
    __builtin_amdgcn_global_load_lds((const __attribute__((address_space(1))) unsigned int*)g,
                                     (__attribute__((address_space(3))) unsigned int*)l,
                                     16, 0, 0);
}

// ---------------- fused prep: cast x (packed u32x2 stores) + transpose w_qkv + w_proj --------
__global__ __launch_bounds__(256) void prep_kernel(const float* __restrict__ x,
                                                   const float* __restrict__ w_qkv,
                                                   const float* __restrict__ w_proj,
                                                   u16* __restrict__ x_bf,
                                                   u16* __restrict__ wqkv_t,
                                                   u16* __restrict__ wproj_t) {
    __shared__ float tile[64][65];
    int bid = blockIdx.x;
    int t = threadIdx.x;
    if (bid < 1024) {
        int base = bid * 4096 + t * 4;
#pragma unroll
        for (int it = 0; it < 4; ++it) {
            int i = base + it * 1024;
            float4 v = *(const float4*)(x + i);
            u32 w0 = (u32)f2bf(v.x) | ((u32)f2bf(v.y) << 16);
            u32 w1 = (u32)f2bf(v.z) | ((u32)f2bf(v.w) << 16);
            *(u32x2*)(x_bf + i) = (u32x2){w0, w1};  // byte addr 8-aligned (i = 4*(...))
        }
        return;
    }
    const float* in;
    u16* out;
    int N, tidx;
    if (bid < 1792) { in = w_qkv; out = wqkv_t; N = 3 * C_; tidx = bid - 1024; }
    else            { in = w_proj; out = wproj_t; N = C_;  tidx = bid - 1792; }
    int ntiles = N / 64;
    int n0 = (tidx % ntiles) * 64, k0 = (tidx / ntiles) * 64;
    int c = t & 63, r0 = t >> 6;
    for (int i = 0; i < 16; ++i) {
        int r = r0 * 16 + i;
        tile[r][c] = in[(size_t)(k0 + r) * N + n0 + c];
    }
    __syncthreads();
    for (int i = 0; i < 16; ++i) {
        int rn = r0 * 16 + i;
        out[(size_t)(n0 + rn) * C_ + k0 + c] = f2bf(tile[c][rn]);
    }
}

// ---------------- fused QKV GEMM, 8-phase 256x256 schedule (T3+T4+T2+T5) ----------------
// barrier -> stage -> vmcnt(2) -> BARRIER -> ds_read: every wave's tile-kt staging loads
// provably complete (vmcnt retired) before ANY wave's ds_read of tile kt. (race-free, R7;
// R9 measured the extra barrier at ~0 cost vs R5's racy variant)
__global__ __launch_bounds__(512, 2) void qkv_gemm(const u16* __restrict__ x_bf,
                                                   const u16* __restrict__ wqkv_t,
                                                   u16* __restrict__ Qo, u16* __restrict__ Ko,
                                                   u16* __restrict__ Vto) {
    __shared__ __align__(16) u16 smem[65536];  // As[2][256][64] = [0:32768], Bs = [32768:65536]
    const int K = 1024;
    int bid = blockIdx.x;
    bool qk = (bid < 128);
    const u16 *A, *Bt;
    int m0, n0;
    if (qk) {
        A = x_bf; Bt = wqkv_t;
        m0 = (bid >> 3) * 256; n0 = (bid & 7) * 256;
    } else {
        int vb = bid - 128;
        A = wqkv_t + 2048 * 1024; Bt = x_bf;
        m0 = (vb >> 4) * 256; n0 = (vb & 15) * 256;
    }
    int t = threadIdx.x;
    int wave = t >> 6, lane = t & 63, lr = lane & 15, quad = lane >> 4;
    int wave_m = wave >> 2, wave_n = wave & 3;
    int wm = wave_m * 128, wn = wave_n * 64;

    u16* As = smem;
    u16* Bs = smem + 32768;

    // staging: lane l -> row (l>>3) of its 8-row group, dest k-chunk (l&7)*8 (linear);
    // source k pre-swizzled by the (row&7) involution so swizzled ds_reads see the right data
    int gk = (((lane & 7) ^ ((lane >> 3) & 7))) * 8;
    int srow8 = wave * 8 + (lane >> 3);  // 0..63 within a 64-row staging group

    f32x4 acc[8][4];
#pragma unroll
    for (int i = 0; i < 8; ++i)
#pragma unroll
        for (int j = 0; j < 4; ++j) acc[i][j] = (f32x4){0.f, 0.f, 0.f, 0.f};

    auto stageA = [&](int buf, int kt, int h) {
#pragma unroll
        for (int j = 0; j < 2; ++j) {
            int row = h * 128 + j * 64 + srow8;
            gll16(&A[(size_t)(m0 + row) * K + kt * 64 + gk],
                  &As[buf * 16384 + (h * 128 + j * 64 + wave * 8) * 64]);
        }
    };
    auto stageB = [&](int buf, int kt, int h) {
#pragma unroll
        for (int j = 0; j < 2; ++j) {
            int row = h * 128 + j * 64 + srow8;
            gll16(&Bt[(size_t)(n0 + row) * K + kt * 64 + gk],
                  &Bs[buf * 16384 + (h * 128 + j * 64 + wave * 8) * 64]);
        }
    };

    bf16x8 aA[4][2], aB[4][2];
    int kswz = ((lr & 7) << 3);
    auto ldA = [&](int buf, int qm) {
        const u16* p = &As[buf * 16384 + (wm + qm * 64) * 64];
#pragma unroll
        for (int mt = 0; mt < 4; ++mt)
#pragma unroll
            for (int kh = 0; kh < 2; ++kh)
                aA[mt][kh] = *(const bf16x8*)&p[(mt * 16 + lr) * 64 + (((kh << 5) | (quad << 3)) ^ kswz)];
    };
    auto ldB = [&](int buf, int qn) {
        const u16* p = &Bs[buf * 16384 + (wn + qn * 32) * 64];
#pragma unroll
        for (int nt = 0; nt < 2; ++nt)
#pragma unroll
            for (int kh = 0; kh < 2; ++kh)
                aB[qn * 2 + nt][kh] = *(const bf16x8*)&p[(nt * 16 + lr) * 64 + (((kh << 5) | (quad << 3)) ^ kswz)];
    };
    auto mfmaQ = [&](int qm, int qn) {
        __builtin_amdgcn_s_setprio(1);
#pragma unroll
        for (int kh = 0; kh < 2; ++kh)
#pragma unroll
            for (int mt = 0; mt < 4; ++mt)
#pragma unroll
                for (int nt = 0; nt < 2; ++nt)
                    acc[qm * 4 + mt][qn * 2 + nt] =
                        mfma16(aA[mt][kh], aB[qn * 2 + nt][kh], acc[qm * 4 + mt][qn * 2 + nt]);
        __builtin_amdgcn_s_setprio(0);
    };

    // prologue: stage tile 0 (4 halves = 8 loads/thread)
    stageA(0, 0, 0); stageA(0, 0, 1); stageB(0, 0, 0); stageB(0, 0, 1);

    for (int kt = 0; kt < 16; ++kt) {
        int buf = kt & 1;
        bool pf = (kt < 15);
        // phase q0 (quadrant m-half0 x n-half0)
        __builtin_amdgcn_s_barrier();  // prev-iter reads of As/Bs[buf^1] all retired
        asm volatile("" ::: "memory");
        if (pf) stageA(buf ^ 1, kt + 1, 0);
        if (pf) asm volatile("s_waitcnt vmcnt(2)" ::: "memory");
        else    asm volatile("s_waitcnt vmcnt(0)" ::: "memory");
        __builtin_amdgcn_s_barrier();  // ALL waves' tile-kt staging complete before any read
        asm volatile("" ::: "memory");
        __builtin_amdgcn_sched_barrier(0);
        ldA(buf, 0); ldB(buf, 0);
        mfmaQ(0, 0);
        // phase q1 (m-half0 x n-half1)
        __builtin_amdgcn_s_barrier();
        asm volatile("" ::: "memory");
        if (pf) stageA(buf ^ 1, kt + 1, 1);
        ldB(buf, 1);
        mfmaQ(0, 1);
        // phase q2 (m-half1 x n-half1)
        __builtin_amdgcn_s_barrier();
        asm volatile("" ::: "memory");
        if (pf) stageB(buf ^ 1, kt + 1, 0);
        ldA(buf, 1);
        mfmaQ(1, 1);
        // phase q3 (m-half1 x n-half0) — aB[0..1] still live from q0
        __builtin_amdgcn_s_barrier();
        asm volatile("" ::: "memory");
        if (pf) stageB(buf ^ 1, kt + 1, 1);
        mfmaQ(1, 0);
    }

    __builtin_amdgcn_s_barrier();
    asm volatile("" ::: "memory");

    // coalesced transposed epilogue (r9/r10 pattern, p extended to 8 m-frags per wave)
    u16* eb = smem + wave * 1152;
    int row = lane >> 2;
    int cb = (lane & 3) * 16;
    if (qk) {
        int colg = n0 + wn;
        int part = colg >> 10;
        int h = (colg & 1023) >> 6;
        float sc = (part == 0) ? QSCALE : 1.0f;
        u16* outb = (part == 0) ? Qo : Ko;
#pragma unroll
        for (int p = 0; p < 8; ++p) {
            asm volatile("" ::: "memory");
#pragma unroll
            for (int nt = 0; nt < 4; ++nt)
#pragma unroll
                for (int r = 0; r < 4; ++r)
                    eb[(quad * 4 + r) * 72 + nt * 16 + lr] = f2bf(acc[p][nt][r] * sc);
            asm volatile("" ::: "memory");
            u16x8 va = *(const u16x8*)(eb + row * 72 + cb);
            u16x8 vb = *(const u16x8*)(eb + row * 72 + cb + 8);
            asm volatile("" ::: "memory");
            int rowg = m0 + wm + p * 16 + row;
            int bb = rowg >> 11, tt = rowg & 2047;
            int bh = bb * H_ + h;
            u32* dst = (u32*)(outb + ((size_t)(bh * T_ + tt)) * D_ + cb);
            *(u32x4*)dst = __builtin_bit_cast(u32x4, va);
            *(u32x4*)(dst + 4) = __builtin_bit_cast(u32x4, vb);
        }
    } else {
#pragma unroll
        for (int p = 0; p < 8; ++p) {
            asm volatile("" ::: "memory");
#pragma unroll
            for (int nt = 0; nt < 4; ++nt)
#pragma unroll
                for (int r = 0; r < 4; ++r)
                    eb[(quad * 4 + r) * 72 + nt * 16 + lr] = f2bf(acc[p][nt][r]);
            asm volatile("" ::: "memory");
            u16x8 va = *(const u16x8*)(eb + row * 72 + cb);
            u16x8 vb = *(const u16x8*)(eb + row * 72 + cb + 8);
            asm volatile("" ::: "memory");
            int rowg = m0 + wm + p * 16 + row;
            int h = rowg >> 6, d = rowg & 63;
            int tg = n0 + wn + cb;
            int bb = tg >> 11, tt = tg & 2047;
            u32* dst = (u32*)(Vto + (((size_t)(bb * H_ + h)) * D_ + d) * T_ + tt);
            *(u32x4*)dst = __builtin_bit_cast(u32x4, va);
            *(u32x4*)(dst + 4) = __builtin_bit_cast(u32x4, vb);
        }
    }
}

// ---------------- proj GEMM 128x128 with dbuf staging + conflict-free swizzle ----------------
// R10: tile 128x64 -> 128x128 (256 blocks x 4 waves, acc[2][8], BK=32, LDS 32KB -> still
// 4 blocks/CU). Halves B LDS-traffic per output, doubles MFMA per fragment-read (m93 step).
// Indexing is the verified pattern with nt extended 4->8 and B staged as 8x16-row chunks.
__global__ __launch_bounds__(256) void gemm128_proj(const u16* __restrict__ A,
                                                    const u16* __restrict__ Bt,
                                                    float* __restrict__ Cout,
                                                    const float* __restrict__ bias,
                                                    int M, int N, int K) {
    __shared__ __align__(16) u16 smem[16384];  // As[2][128][32]=[0:8192], Bs[2][128][32]=[8192:16384]
    int m0 = blockIdx.y * 128, n0 = blockIdx.x * 128;
    int t = threadIdx.x;
    int wave = t >> 6, lane = t & 63, lr = lane & 15, quad = lane >> 4;
    int srow = lane >> 2;
    int sgl = (lane & 3) ^ ((srow >> 1) & 3);
    int swz = (quad ^ ((lr >> 1) & 3)) * 8;

    f32x4 acc[2][8];
#pragma unroll
    for (int i = 0; i < 2; ++i)
#pragma unroll
        for (int j = 0; j < 8; ++j) acc[i][j] = (f32x4){0.f, 0.f, 0.f, 0.f};

    auto stage = [&](int b, int kb) {
        u16* As = smem + b * 4096;
        u16* Bs = smem + 8192 + b * 4096;
#pragma unroll
        for (int i = 0; i < 2; ++i) {
            int c = wave * 2 + i;
            int row = c * 16 + srow;
            gll16(&A[(size_t)(m0 + row) * K + kb + sgl * 8], &As[c * 512]);
            gll16(&Bt[(size_t)(n0 + row) * K + kb + sgl * 8], &Bs[c * 512]);
        }
    };

    int niter = K / 32;
    stage(0, 0);
    for (int kt = 0; kt < niter; ++kt) {
        int buf = kt & 1;
        __syncthreads();
        if (kt < niter - 1) stage(buf ^ 1, (kt + 1) * 32);
        const u16* As = smem + buf * 4096;
        const u16* Bs = smem + 8192 + buf * 4096;
        bf16x8 af[2], bfr[8];
#pragma unroll
        for (int mt = 0; mt < 2; ++mt)
            af[mt] = *(const bf16x8*)&As[(wave * 32 + mt * 16 + lr) * 32 + swz];
#pragma unroll
        for (int nt = 0; nt < 8; ++nt)
            bfr[nt] = *(const bf16x8*)&Bs[(nt * 16 + lr) * 32 + swz];
#pragma unroll
        for (int mt = 0; mt < 2; ++mt)
#pragma unroll
            for (int nt = 0; nt < 8; ++nt) acc[mt][nt] = mfma16(af[mt], bfr[nt], acc[mt][nt]);
    }

#pragma unroll
    for (int mt = 0; mt < 2; ++mt)
#pragma unroll
        for (int nt = 0; nt < 8; ++nt)
#pragma unroll
            for (int r = 0; r < 4; ++r) {
                int rowg = m0 + wave * 32 + mt * 16 + quad * 4 + r;
                int col = n0 + nt * 16 + lr;
                Cout[(size_t)rowg * N + col] = acc[mt][nt][r] + bias[col];
            }
}

// ---------------- flash attention (r7 structure + T5 setprio, dbuf V — best measured) --------
__global__ __launch_bounds__(256, 4) void attn_kernel(const u16* __restrict__ Q,
                                                      const u16* __restrict__ Kb,
                                                      const u16* __restrict__ Vt,
                                                      u16* __restrict__ Y) {
    __shared__ __align__(16) u16 Kls[2][64 * 64];
    __shared__ __align__(16) u16 Vls[2][64 * 64];
    __shared__ __align__(16) u32 Pls[4][512];
    int qt = 31 - (blockIdx.x >> 5);  // heavy-first
    int bh = blockIdx.x & 31;
    int t = threadIdx.x, wave = t >> 6, lane = t & 63, lr = lane & 15, quad = lane >> 4;

    const u16* kbase = Kb + (size_t)bh * (T_ * D_);
    const u16* vbase = Vt + (size_t)bh * (D_ * T_);
    const u16* Qg = Q + ((size_t)bh * T_ + qt * 64 + wave * 16 + lr) * D_;
    bf16x8 qfl = *(const bf16x8*)(Qg + quad * 8);
    bf16x8 qfh = *(const bf16x8*)(Qg + 32 + quad * 8);

    float lsum = 0.f;
    f32x4 o[4];
#pragma unroll
    for (int dt = 0; dt < 4; ++dt) o[dt] = (f32x4){0.f, 0.f, 0.f, 0.f};

    int srow = lane >> 3;
    int sgl = (lane & 7) ^ srow;
    int swz1 = (quad ^ (lr & 7)) * 8;
    int swz2 = ((quad + 4) ^ (lr & 7)) * 8;
    u32* pw = &Pls[wave][0];
    int pwbase = lr * 32 + (quad & 1) * 2;
    int rg1 = (quad ^ (lr & 7)) << 2;
    int rg2 = ((quad + 4) ^ (lr & 7)) << 2;

    for (int i = 0; i < 2; ++i) {
        int c = wave * 2 + i;
        int row = c * 8 + srow;
        gll16(kbase + (size_t)row * D_ + sgl * 8, &Kls[0][c * 512]);
        gll16(vbase + (size_t)row * T_ + sgl * 8, &Vls[0][c * 512]);
    }

    for (int kt = 0; kt <= qt; ++kt) {
        int buf = kt & 1;
        __syncthreads();
        if (kt < qt) {
            int nk = kt + 1;
            for (int i = 0; i < 2; ++i) {
                int c = wave * 2 + i;
                int row = c * 8 + srow;
                gll16(kbase + (size_t)(nk * 64 + row) * D_ + sgl * 8, &Kls[buf ^ 1][c * 512]);
                gll16(vbase + (size_t)row * T_ + nk * 64 + sgl * 8, &Vls[buf ^ 1][c * 512]);
            }
        }
        bf16x8 kf0[4], kf1[4], vf0[4], vf1[4];
#pragma unroll
        for (int st = 0; st < 4; ++st) {
            const u16* kp = &Kls[buf][(st * 16 + lr) * 64];
            kf0[st] = *(const bf16x8*)(kp + swz1);
            kf1[st] = *(const bf16x8*)(kp + swz2);
            const u16* vp = &Vls[buf][(st * 16 + lr) * 64];
            vf0[st] = *(const bf16x8*)(vp + swz1);
            vf1[st] = *(const bf16x8*)(vp + swz2);
        }
        f32x4 s[4];
        __builtin_amdgcn_s_setprio(1);
#pragma unroll
        for (int st = 0; st < 4; ++st) {
            s[st] = mfma16(kf0[st], qfl, (f32x4){0.f, 0.f, 0.f, 0.f});
            s[st] = mfma16(kf1[st], qfh, s[st]);
        }
        __builtin_amdgcn_s_setprio(0);
        if (kt == qt) {
            int qloc = wave * 16 + lr;
#pragma unroll
            for (int st = 0; st < 4; ++st)
#pragma unroll
                for (int r = 0; r < 4; ++r) {
                    if (st * 16 + quad * 4 + r > qloc) s[st][r] = -__builtin_inff();
                }
        }
        float sum = 0.f;
#pragma unroll
        for (int st = 0; st < 4; ++st)
#pragma unroll
            for (int r = 0; r < 4; ++r) {
                float p = __builtin_amdgcn_exp2f(s[st][r]);
                s[st][r] = p;
                sum += p;
            }
        sum += __shfl_xor(sum, 16);
        sum += __shfl_xor(sum, 32);
        lsum += sum;
        asm volatile("" ::: "memory");
#pragma unroll
        for (int st = 0; st < 4; ++st)
#pragma unroll
            for (int rp = 0; rp < 2; ++rp) {
                u32 lo = f2bf(s[st][2 * rp]);
                u32 hi = f2bf(s[st][2 * rp + 1]);
                pw[pwbase + (((st * 2 + (quad >> 1)) ^ (lr & 7)) << 2) + rp] = lo | (hi << 16);
            }
        asm volatile("" ::: "memory");
        const u32* prow = &pw[lr * 32];
        u32x4 plo = *(const u32x4*)(prow + rg1);
        u32x4 phi = *(const u32x4*)(prow + rg2);
        asm volatile("" ::: "memory");
        bf16x8 pfl = __builtin_bit_cast(bf16x8, plo);
        bf16x8 pfh = __builtin_bit_cast(bf16x8, phi);
        __builtin_amdgcn_s_setprio(1);
#pragma unroll
        for (int dt = 0; dt < 4; ++dt) {
            o[dt] = mfma16(vf0[dt], pfl, o[dt]);
            o[dt] = mfma16(vf1[dt], pfh, o[dt]);
        }
        __builtin_amdgcn_s_setprio(0);
    }

    int b = bh >> 4, h = bh & 15;
    float inv = 1.0f / lsum;
    asm volatile("" ::: "memory");
#pragma unroll
    for (int dt = 0; dt < 4; ++dt)
#pragma unroll
        for (int rp = 0; rp < 2; ++rp) {
            u32 lo = f2bf(o[dt][2 * rp] * inv);
            u32 hi = f2bf(o[dt][2 * rp + 1] * inv);
            pw[pwbase + (((dt * 2 + (quad >> 1)) ^ (lr & 7)) << 2) + rp] = lo | (hi << 16);
        }
    asm volatile("" ::: "memory");
    {
        int query = lane >> 2, wsel = lane & 3;
        const u32* prow = &pw[query * 32];
        u32x4 w0 = *(const u32x4*)(prow + (((wsel * 2) ^ (query & 7)) << 2));
        u32x4 w1 = *(const u32x4*)(prow + (((wsel * 2 + 1) ^ (query & 7)) << 2));
        u32* dst = (u32*)(Y + ((size_t)(b * T_ + qt * 64 + wave * 16 + query)) * C_ + h * 64 + wsel * 16);
        *(u32x4*)dst = w0;
        *(u32x4*)(dst + 4) = w1;
    }
}

extern "C" void kernel_launch(void* const* d_in, const int* in_sizes, int n_in,
                              void* d_out, int out_size, void* d_ws, size_t ws_size,
                              hipStream_t stream) {
    const float* x      = (const float*)d_in[0];
    const float* w_qkv  = (const float*)d_in[1];
    const float* w_proj = (const float*)d_in[2];
    const float* b_proj = (const float*)d_in[3];
    float* out = (float*)d_out;

    char* ws = (char*)d_ws;
    u16* x_bf    = (u16*)(ws + 0);          // 8 MB
    u16* wqkv_t  = (u16*)(ws + 8388608);    // 6 MB [n=3072][k=1024]
    u16* wproj_t = (u16*)(ws + 14680064);   // 2 MB
    u16* q_bf    = (u16*)(ws + 16777216);   // 8 MB  [bh][t][d] (pre-scaled)
    u16* k_bf    = (u16*)(ws + 25165824);   // 8 MB  [bh][t][d]
    u16* vt_bf   = (u16*)(ws + 33554432);   // 8 MB  [bh][d][t]
    u16* y_bf    = (u16*)(ws + 41943040);   // 8 MB  [b*t][c]

    const int M = B_ * T_;  // 4096

    // fused prep: cast + both weight transposes (2048 blocks)
    prep_kernel<<<2048, 256, 0, stream>>>(x, w_qkv, w_proj, x_bf, wqkv_t, wproj_t);

    // fused QKV: 8-phase 256x256 schedule, 192 blocks x 512 threads (race-free)
    qkv_gemm<<<192, 512, 0, stream>>>(x_bf, wqkv_t, q_bf, k_bf, vt_bf);

    // flash attention: 1024 4-wave blocks (dbuf V, best measured), heavy-first
    attn_kernel<<<32 * (T_ / 64), 256, 0, stream>>>(q_bf, k_bf, vt_bf, y_bf);

    // proj gemm: [4096,1024] x [1024,1024]^T + bias (256 blocks, 128x128 tiles)
    gemm128_proj<<<dim3(C_ / 128, M / 128), 256, 0, stream>>>(
        y_bf, wproj_t, out, b_proj, M, C_, C_);
}

// Round 11
// 166.755 us; speedup vs baseline: 1.0096x; 1.0096x over previous
//
#include <hip/hip_runtime.h>

typedef __bf16 bf16x8 __attribute__((ext_vector_type(8)));
typedef float f32x4 __attribute__((ext_vector_type(4)));
typedef unsigned short u16;
typedef unsigned int u32;
typedef u32 u32x4 __attribute__((ext_vector_type(4)));
typedef u32 u32x2 __attribute__((ext_vector_type(2)));
typedef u16 u16x8 __attribute__((ext_vector_type(8)));

#define B_ 2
#define T_ 2048
#define C_ 1024
#define H_ 16
#define D_ 64
// 0.125 * log2(e): folded into Q so attn softmax runs in exp2 domain
#define QSCALE 0.18033688011112042f

// RNE f32->bf16 via the compiler's native path (m240: scalar cast is the fast path;
// pairs fuse to v_cvt_pk_bf16_f32). Replaces the 5-op manual RNE emulation.
__device__ __forceinline__ u16 f2bf(float f) {
    return __builtin_bit_cast(u16, (__bf16)f);
}

__device__ __forceinline__ f32x4 mfma16(bf16x8 a, bf16x8 b, f32x4 c) {
    return __builtin_amdgcn_mfma_f32_16x16x32_bf16(a, b, c, 0, 0, 0);
}

// async global->LDS, 16B per lane; LDS dest = wave-uniform base + lane*16
__device__ __forceinline__ void gll16(const u16* g, u16* l) {
    __builtin_amdgcn_global_load_lds((const __attribute__((address_space(1))) unsigned int*)g,
                                     (__attribute__((address_space(3))) unsigned int*)l,
                                     16, 0, 0);
}

// ---------------- fused prep: cast x (packed u32x2 stores) + transpose w_qkv + w_proj --------
__global__ __launch_bounds__(256) void prep_kernel(const float* __restrict__ x,
                                                   const float* __restrict__ w_qkv,
                                                   const float* __restrict__ w_proj,
                                                   u16* __restrict__ x_bf,
                                                   u16* __restrict__ wqkv_t,
                                                   u16* __restrict__ wproj_t) {
    __shared__ float tile[64][65];
    int bid = blockIdx.x;
    int t = threadIdx.x;
    if (bid < 1024) {
        int base = bid * 4096 + t * 4;
#pragma unroll
        for (int it = 0; it < 4; ++it) {
            int i = base + it * 1024;
            float4 v = *(const float4*)(x + i);
            u32 w0 = (u32)f2bf(v.x) | ((u32)f2bf(v.y) << 16);
            u32 w1 = (u32)f2bf(v.z) | ((u32)f2bf(v.w) << 16);
            *(u32x2*)(x_bf + i) = (u32x2){w0, w1};  // byte addr 8-aligned (i = 4*(...))
        }
        return;
    }
    const float* in;
    u16* out;
    int N, tidx;
    if (bid < 1792) { in = w_qkv; out = wqkv_t; N = 3 * C_; tidx = bid - 1024; }
    else            { in = w_proj; out = wproj_t; N = C_;  tidx = bid - 1792; }
    int ntiles = N / 64;
    int n0 = (tidx % ntiles) * 64, k0 = (tidx / ntiles) * 64;
    int c = t & 63, r0 = t >> 6;
    for (int i = 0; i < 16; ++i) {
        int r = r0 * 16 + i;
        tile[r][c] = in[(size_t)(k0 + r) * N + n0 + c];
    }
    __syncthreads();
    for (int i = 0; i < 16; ++i) {
        int rn = r0 * 16 + i;
        out[(size_t)(n0 + rn) * C_ + k0 + c] = f2bf(tile[c][rn]);
    }
}

// ---------------- fused QKV GEMM, 8-phase 256x256 schedule (T3+T4+T2+T5) ----------------
// barrier -> stage -> vmcnt(2) -> BARRIER -> ds_read: every wave's tile-kt staging loads
// provably complete (vmcnt retired) before ANY wave's ds_read of tile kt. (race-free, R7;
// R9 measured the extra barrier at ~0 cost vs R5's racy variant)
__global__ __launch_bounds__(512, 2) void qkv_gemm(const u16* __restrict__ x_bf,
                                                   const u16* __restrict__ wqkv_t,
                                                   u16* __restrict__ Qo, u16* __restrict__ Ko,
                                                   u16* __restrict__ Vto) {
    __shared__ __align__(16) u16 smem[65536];  // As[2][256][64] = [0:32768], Bs = [32768:65536]
    const int K = 1024;
    int bid = blockIdx.x;
    bool qk = (bid < 128);
    const u16 *A, *Bt;
    int m0, n0;
    if (qk) {
        A = x_bf; Bt = wqkv_t;
        m0 = (bid >> 3) * 256; n0 = (bid & 7) * 256;
    } else {
        int vb = bid - 128;
        A = wqkv_t + 2048 * 1024; Bt = x_bf;
        m0 = (vb >> 4) * 256; n0 = (vb & 15) * 256;
    }
    int t = threadIdx.x;
    int wave = t >> 6, lane = t & 63, lr = lane & 15, quad = lane >> 4;
    int wave_m = wave >> 2, wave_n = wave & 3;
    int wm = wave_m * 128, wn = wave_n * 64;

    u16* As = smem;
    u16* Bs = smem + 32768;

    // staging: lane l -> row (l>>3) of its 8-row group, dest k-chunk (l&7)*8 (linear);
    // source k pre-swizzled by the (row&7) involution so swizzled ds_reads see the right data
    int gk = (((lane & 7) ^ ((lane >> 3) & 7))) * 8;
    int srow8 = wave * 8 + (lane >> 3);  // 0..63 within a 64-row staging group

    f32x4 acc[8][4];
#pragma unroll
    for (int i = 0; i < 8; ++i)
#pragma unroll
        for (int j = 0; j < 4; ++j) acc[i][j] = (f32x4){0.f, 0.f, 0.f, 0.f};

    auto stageA = [&](int buf, int kt, int h) {
#pragma unroll
        for (int j = 0; j < 2; ++j) {
            int row = h * 128 + j * 64 + srow8;
            gll16(&A[(size_t)(m0 + row) * K + kt * 64 + gk],
                  &As[buf * 16384 + (h * 128 + j * 64 + wave * 8) * 64]);
        }
    };
    auto stageB = [&](int buf, int kt, int h) {
#pragma unroll
        for (int j = 0; j < 2; ++j) {
            int row = h * 128 + j * 64 + srow8;
            gll16(&Bt[(size_t)(n0 + row) * K + kt * 64 + gk],
                  &Bs[buf * 16384 + (h * 128 + j * 64 + wave * 8) * 64]);
        }
    };

    bf16x8 aA[4][2], aB[4][2];
    int kswz = ((lr & 7) << 3);
    auto ldA = [&](int buf, int qm) {
        const u16* p = &As[buf * 16384 + (wm + qm * 64) * 64];
#pragma unroll
        for (int mt = 0; mt < 4; ++mt)
#pragma unroll
            for (int kh = 0; kh < 2; ++kh)
                aA[mt][kh] = *(const bf16x8*)&p[(mt * 16 + lr) * 64 + (((kh << 5) | (quad << 3)) ^ kswz)];
    };
    auto ldB = [&](int buf, int qn) {
        const u16* p = &Bs[buf * 16384 + (wn + qn * 32) * 64];
#pragma unroll
        for (int nt = 0; nt < 2; ++nt)
#pragma unroll
            for (int kh = 0; kh < 2; ++kh)
                aB[qn * 2 + nt][kh] = *(const bf16x8*)&p[(nt * 16 + lr) * 64 + (((kh << 5) | (quad << 3)) ^ kswz)];
    };
    auto mfmaQ = [&](int qm, int qn) {
        __builtin_amdgcn_s_setprio(1);
#pragma unroll
        for (int kh = 0; kh < 2; ++kh)
#pragma unroll
            for (int mt = 0; mt < 4; ++mt)
#pragma unroll
                for (int nt = 0; nt < 2; ++nt)
                    acc[qm * 4 + mt][qn * 2 + nt] =
                        mfma16(aA[mt][kh], aB[qn * 2 + nt][kh], acc[qm * 4 + mt][qn * 2 + nt]);
        __builtin_amdgcn_s_setprio(0);
    };

    // prologue: stage tile 0 (4 halves = 8 loads/thread)
    stageA(0, 0, 0); stageA(0, 0, 1); stageB(0, 0, 0); stageB(0, 0, 1);

    for (int kt = 0; kt < 16; ++kt) {
        int buf = kt & 1;
        bool pf = (kt < 15);
        // phase q0 (quadrant m-half0 x n-half0)
        __builtin_amdgcn_s_barrier();  // prev-iter reads of As/Bs[buf^1] all retired
        asm volatile("" ::: "memory");
        if (pf) stageA(buf ^ 1, kt + 1, 0);
        if (pf) asm volatile("s_waitcnt vmcnt(2)" ::: "memory");
        else    asm volatile("s_waitcnt vmcnt(0)" ::: "memory");
        __builtin_amdgcn_s_barrier();  // ALL waves' tile-kt staging complete before any read
        asm volatile("" ::: "memory");
        __builtin_amdgcn_sched_barrier(0);
        ldA(buf, 0); ldB(buf, 0);
        mfmaQ(0, 0);
        // phase q1 (m-half0 x n-half1)
        __builtin_amdgcn_s_barrier();
        asm volatile("" ::: "memory");
        if (pf) stageA(buf ^ 1, kt + 1, 1);
        ldB(buf, 1);
        mfmaQ(0, 1);
        // phase q2 (m-half1 x n-half1)
        __builtin_amdgcn_s_barrier();
        asm volatile("" ::: "memory");
        if (pf) stageB(buf ^ 1, kt + 1, 0);
        ldA(buf, 1);
        mfmaQ(1, 1);
        // phase q3 (m-half1 x n-half0) — aB[0..1] still live from q0
        __builtin_amdgcn_s_barrier();
        asm volatile("" ::: "memory");
        if (pf) stageB(buf ^ 1, kt + 1, 1);
        mfmaQ(1, 0);
    }

    __builtin_amdgcn_s_barrier();
    asm volatile("" ::: "memory");

    // coalesced transposed epilogue (r9/r10 pattern, p extended to 8 m-frags per wave)
    u16* eb = smem + wave * 1152;
    int row = lane >> 2;
    int cb = (lane & 3) * 16;
    if (qk) {
        int colg = n0 + wn;
        int part = colg >> 10;
        int h = (colg & 1023) >> 6;
        float sc = (part == 0) ? QSCALE : 1.0f;
        u16* outb = (part == 0) ? Qo : Ko;
#pragma unroll
        for (int p = 0; p < 8; ++p) {
            asm volatile("" ::: "memory");
#pragma unroll
            for (int nt = 0; nt < 4; ++nt)
#pragma unroll
                for (int r = 0; r < 4; ++r)
                    eb[(quad * 4 + r) * 72 + nt * 16 + lr] = f2bf(acc[p][nt][r] * sc);
            asm volatile("" ::: "memory");
            u16x8 va = *(const u16x8*)(eb + row * 72 + cb);
            u16x8 vb = *(const u16x8*)(eb + row * 72 + cb + 8);
            asm volatile("" ::: "memory");
            int rowg = m0 + wm + p * 16 + row;
            int bb = rowg >> 11, tt = rowg & 2047;
            int bh = bb * H_ + h;
            u32* dst = (u32*)(outb + ((size_t)(bh * T_ + tt)) * D_ + cb);
            *(u32x4*)dst = __builtin_bit_cast(u32x4, va);
            *(u32x4*)(dst + 4) = __builtin_bit_cast(u32x4, vb);
        }
    } else {
#pragma unroll
        for (int p = 0; p < 8; ++p) {
            asm volatile("" ::: "memory");
#pragma unroll
            for (int nt = 0; nt < 4; ++nt)
#pragma unroll
                for (int r = 0; r < 4; ++r)
                    eb[(quad * 4 + r) * 72 + nt * 16 + lr] = f2bf(acc[p][nt][r]);
            asm volatile("" ::: "memory");
            u16x8 va = *(const u16x8*)(eb + row * 72 + cb);
            u16x8 vb = *(const u16x8*)(eb + row * 72 + cb + 8);
            asm volatile("" ::: "memory");
            int rowg = m0 + wm + p * 16 + row;
            int h = rowg >> 6, d = rowg & 63;
            int tg = n0 + wn + cb;
            int bb = tg >> 11, tt = tg & 2047;
            u32* dst = (u32*)(Vto + (((size_t)(bb * H_ + h)) * D_ + d) * T_ + tt);
            *(u32x4*)dst = __builtin_bit_cast(u32x4, va);
            *(u32x4*)(dst + 4) = __builtin_bit_cast(u32x4, vb);
        }
    }
}

// ---------------- proj GEMM 128x128 with dbuf staging + conflict-free swizzle ----------------
__global__ __launch_bounds__(256) void gemm128_proj(const u16* __restrict__ A,
                                                    const u16* __restrict__ Bt,
                                                    float* __restrict__ Cout,
                                                    const float* __restrict__ bias,
                                                    int M, int N, int K) {
    __shared__ __align__(16) u16 smem[16384];  // As[2][128][32]=[0:8192], Bs[2][128][32]=[8192:16384]
    int m0 = blockIdx.y * 128, n0 = blockIdx.x * 128;
    int t = threadIdx.x;
    int wave = t >> 6, lane = t & 63, lr = lane & 15, quad = lane >> 4;
    int srow = lane >> 2;
    int sgl = (lane & 3) ^ ((srow >> 1) & 3);
    int swz = (quad ^ ((lr >> 1) & 3)) * 8;

    f32x4 acc[2][8];
#pragma unroll
    for (int i = 0; i < 2; ++i)
#pragma unroll
        for (int j = 0; j < 8; ++j) acc[i][j] = (f32x4){0.f, 0.f, 0.f, 0.f};

    auto stage = [&](int b, int kb) {
        u16* As = smem + b * 4096;
        u16* Bs = smem + 8192 + b * 4096;
#pragma unroll
        for (int i = 0; i < 2; ++i) {
            int c = wave * 2 + i;
            int row = c * 16 + srow;
            gll16(&A[(size_t)(m0 + row) * K + kb + sgl * 8], &As[c * 512]);
            gll16(&Bt[(size_t)(n0 + row) * K + kb + sgl * 8], &Bs[c * 512]);
        }
    };

    int niter = K / 32;
    stage(0, 0);
    for (int kt = 0; kt < niter; ++kt) {
        int buf = kt & 1;
        __syncthreads();
        if (kt < niter - 1) stage(buf ^ 1, (kt + 1) * 32);
        const u16* As = smem + buf * 4096;
        const u16* Bs = smem + 8192 + buf * 4096;
        bf16x8 af[2], bfr[8];
#pragma unroll
        for (int mt = 0; mt < 2; ++mt)
            af[mt] = *(const bf16x8*)&As[(wave * 32 + mt * 16 + lr) * 32 + swz];
#pragma unroll
        for (int nt = 0; nt < 8; ++nt)
            bfr[nt] = *(const bf16x8*)&Bs[(nt * 16 + lr) * 32 + swz];
#pragma unroll
        for (int mt = 0; mt < 2; ++mt)
#pragma unroll
            for (int nt = 0; nt < 8; ++nt) acc[mt][nt] = mfma16(af[mt], bfr[nt], acc[mt][nt]);
    }

#pragma unroll
    for (int mt = 0; mt < 2; ++mt)
#pragma unroll
        for (int nt = 0; nt < 8; ++nt)
#pragma unroll
            for (int r = 0; r < 4; ++r) {
                int rowg = m0 + wave * 32 + mt * 16 + quad * 4 + r;
                int col = n0 + nt * 16 + lr;
                Cout[(size_t)rowg * N + col] = acc[mt][nt][r] + bias[col];
            }
}

// ---------------- flash attention (r7 structure + T5 setprio, dbuf V — best measured) --------
__global__ __launch_bounds__(256, 4) void attn_kernel(const u16* __restrict__ Q,
                                                      const u16* __restrict__ Kb,
                                                      const u16* __restrict__ Vt,
                                                      u16* __restrict__ Y) {
    __shared__ __align__(16) u16 Kls[2][64 * 64];
    __shared__ __align__(16) u16 Vls[2][64 * 64];
    __shared__ __align__(16) u32 Pls[4][512];
    int qt = 31 - (blockIdx.x >> 5);  // heavy-first
    int bh = blockIdx.x & 31;
    int t = threadIdx.x, wave = t >> 6, lane = t & 63, lr = lane & 15, quad = lane >> 4;

    const u16* kbase = Kb + (size_t)bh * (T_ * D_);
    const u16* vbase = Vt + (size_t)bh * (D_ * T_);
    const u16* Qg = Q + ((size_t)bh * T_ + qt * 64 + wave * 16 + lr) * D_;
    bf16x8 qfl = *(const bf16x8*)(Qg + quad * 8);
    bf16x8 qfh = *(const bf16x8*)(Qg + 32 + quad * 8);

    float lsum = 0.f;
    f32x4 o[4];
#pragma unroll
    for (int dt = 0; dt < 4; ++dt) o[dt] = (f32x4){0.f, 0.f, 0.f, 0.f};

    int srow = lane >> 3;
    int sgl = (lane & 7) ^ srow;
    int swz1 = (quad ^ (lr & 7)) * 8;
    int swz2 = ((quad + 4) ^ (lr & 7)) * 8;
    u32* pw = &Pls[wave][0];
    int pwbase = lr * 32 + (quad & 1) * 2;
    int rg1 = (quad ^ (lr & 7)) << 2;
    int rg2 = ((quad + 4) ^ (lr & 7)) << 2;

    for (int i = 0; i < 2; ++i) {
        int c = wave * 2 + i;
        int row = c * 8 + srow;
        gll16(kbase + (size_t)row * D_ + sgl * 8, &Kls[0][c * 512]);
        gll16(vbase + (size_t)row * T_ + sgl * 8, &Vls[0][c * 512]);
    }

    for (int kt = 0; kt <= qt; ++kt) {
        int buf = kt & 1;
        __syncthreads();
        if (kt < qt) {
            int nk = kt + 1;
            for (int i = 0; i < 2; ++i) {
                int c = wave * 2 + i;
                int row = c * 8 + srow;
                gll16(kbase + (size_t)(nk * 64 + row) * D_ + sgl * 8, &Kls[buf ^ 1][c * 512]);
                gll16(vbase + (size_t)row * T_ + nk * 64 + sgl * 8, &Vls[buf ^ 1][c * 512]);
            }
        }
        bf16x8 kf0[4], kf1[4], vf0[4], vf1[4];
#pragma unroll
        for (int st = 0; st < 4; ++st) {
            const u16* kp = &Kls[buf][(st * 16 + lr) * 64];
            kf0[st] = *(const bf16x8*)(kp + swz1);
            kf1[st] = *(const bf16x8*)(kp + swz2);
            const u16* vp = &Vls[buf][(st * 16 + lr) * 64];
            vf0[st] = *(const bf16x8*)(vp + swz1);
            vf1[st] = *(const bf16x8*)(vp + swz2);
        }
        f32x4 s[4];
        __builtin_amdgcn_s_setprio(1);
#pragma unroll
        for (int st = 0; st < 4; ++st) {
            s[st] = mfma16(kf0[st], qfl, (f32x4){0.f, 0.f, 0.f, 0.f});
            s[st] = mfma16(kf1[st], qfh, s[st]);
        }
        __builtin_amdgcn_s_setprio(0);
        if (kt == qt) {
            int qloc = wave * 16 + lr;
#pragma unroll
            for (int st = 0; st < 4; ++st)
#pragma unroll
                for (int r = 0; r < 4; ++r) {
                    if (st * 16 + quad * 4 + r > qloc) s[st][r] = -__builtin_inff();
                }
        }
        float sum = 0.f;
#pragma unroll
        for (int st = 0; st < 4; ++st)
#pragma unroll
            for (int r = 0; r < 4; ++r) {
                float p = __builtin_amdgcn_exp2f(s[st][r]);
                s[st][r] = p;
                sum += p;
            }
        sum += __shfl_xor(sum, 16);
        sum += __shfl_xor(sum, 32);
        lsum += sum;
        asm volatile("" ::: "memory");
#pragma unroll
        for (int st = 0; st < 4; ++st)
#pragma unroll
            for (int rp = 0; rp < 2; ++rp) {
                u32 lo = f2bf(s[st][2 * rp]);
                u32 hi = f2bf(s[st][2 * rp + 1]);
                pw[pwbase + (((st * 2 + (quad >> 1)) ^ (lr & 7)) << 2) + rp] = lo | (hi << 16);
            }
        asm volatile("" ::: "memory");
        const u32* prow = &pw[lr * 32];
        u32x4 plo = *(const u32x4*)(prow + rg1);
        u32x4 phi = *(const u32x4*)(prow + rg2);
        asm volatile("" ::: "memory");
        bf16x8 pfl = __builtin_bit_cast(bf16x8, plo);
        bf16x8 pfh = __builtin_bit_cast(bf16x8, phi);
        __builtin_amdgcn_s_setprio(1);
#pragma unroll
        for (int dt = 0; dt < 4; ++dt) {
            o[dt] = mfma16(vf0[dt], pfl, o[dt]);
            o[dt] = mfma16(vf1[dt], pfh, o[dt]);
        }
        __builtin_amdgcn_s_setprio(0);
    }

    int b = bh >> 4, h = bh & 15;
    float inv = 1.0f / lsum;
    asm volatile("" ::: "memory");
#pragma unroll
    for (int dt = 0; dt < 4; ++dt)
#pragma unroll
        for (int rp = 0; rp < 2; ++rp) {
            u32 lo = f2bf(o[dt][2 * rp] * inv);
            u32 hi = f2bf(o[dt][2 * rp + 1] * inv);
            pw[pwbase + (((dt * 2 + (quad >> 1)) ^ (lr & 7)) << 2) + rp] = lo | (hi << 16);
        }
    asm volatile("" ::: "memory");
    {
        int query = lane >> 2, wsel = lane & 3;
        const u32* prow = &pw[query * 32];
        u32x4 w0 = *(const u32x4*)(prow + (((wsel * 2) ^ (query & 7)) << 2));
        u32x4 w1 = *(const u32x4*)(prow + (((wsel * 2 + 1) ^ (query & 7)) << 2));
        u32* dst = (u32*)(Y + ((size_t)(b * T_ + qt * 64 + wave * 16 + query)) * C_ + h * 64 + wsel * 16);
        *(u32x4*)dst = w0;
        *(u32x4*)(dst + 4) = w1;
    }
}

extern "C" void kernel_launch(void* const* d_in, const int* in_sizes, int n_in,
                              void* d_out, int out_size, void* d_ws, size_t ws_size,
                              hipStream_t stream) {
    const float* x      = (const float*)d_in[0];
    const float* w_qkv  = (const float*)d_in[1];
    const float* w_proj = (const float*)d_in[2];
    const float* b_proj = (const float*)d_in[3];
    float* out = (float*)d_out;

    char* ws = (char*)d_ws;
    u16* x_bf    = (u16*)(ws + 0);          // 8 MB
    u16* wqkv_t  = (u16*)(ws + 8388608);    // 6 MB [n=3072][k=1024]
    u16* wproj_t = (u16*)(ws + 14680064);   // 2 MB
    u16* q_bf    = (u16*)(ws + 16777216);   // 8 MB  [bh][t][d] (pre-scaled)
    u16* k_bf    = (u16*)(ws + 25165824);   // 8 MB  [bh][t][d]
    u16* vt_bf   = (u16*)(ws + 33554432);   // 8 MB  [bh][d][t]
    u16* y_bf    = (u16*)(ws + 41943040);   // 8 MB  [b*t][c]

    const int M = B_ * T_;  // 4096

    // fused prep: cast + both weight transposes (2048 blocks)
    prep_kernel<<<2048, 256, 0, stream>>>(x, w_qkv, w_proj, x_bf, wqkv_t, wproj_t);

    // fused QKV: 8-phase 256x256 schedule, 192 blocks x 512 threads (race-free)
    qkv_gemm<<<192, 512, 0, stream>>>(x_bf, wqkv_t, q_bf, k_bf, vt_bf);

    // flash attention: 1024 4-wave blocks (dbuf V, best measured), heavy-first
    attn_kernel<<<32 * (T_ / 64), 256, 0, stream>>>(q_bf, k_bf, vt_bf, y_bf);

    // proj gemm: [4096,1024] x [1024,1024]^T + bias (256 blocks, 128x128 tiles)
    gemm128_proj<<<dim3(C_ / 128, M / 128), 256, 0, stream>>>(
        y_bf, wproj_t, out, b_proj, M, C_, C_);
}

// Round 12
// 166.709 us; speedup vs baseline: 1.0098x; 1.0003x over previous
//
#include <hip/hip_runtime.h>

typedef __bf16 bf16x8 __attribute__((ext_vector_type(8)));
typedef float f32x4 __attribute__((ext_vector_type(4)));
typedef unsigned short u16;
typedef unsigned int u32;
typedef u32 u32x4 __attribute__((ext_vector_type(4)));
typedef u32 u32x2 __attribute__((ext_vector_type(2)));
typedef u16 u16x8 __attribute__((ext_vector_type(8)));

#define B_ 2
#define T_ 2048
#define C_ 1024
#define H_ 16
#define D_ 64
// 0.125 * log2(e): folded into Q so attn softmax runs in exp2 domain
#define QSCALE 0.18033688011112042f

// RNE f32->bf16 via the compiler's native path (m240: scalar cast is the fast path;
// pairs fuse to v_cvt_pk_bf16_f32).
__device__ __forceinline__ u16 f2bf(float f) {
    return __builtin_bit_cast(u16, (__bf16)f);
}

__device__ __forceinline__ u32 pk2(float a, float b) {
    return (u32)f2bf(a) | ((u32)f2bf(b) << 16);
}

__device__ __forceinline__ f32x4 mfma16(bf16x8 a, bf16x8 b, f32x4 c) {
    return __builtin_amdgcn_mfma_f32_16x16x32_bf16(a, b, c, 0, 0, 0);
}

// async global->LDS, 16B per lane; LDS dest = wave-uniform base + lane*16
__device__ __forceinline__ void gll16(const u16* g, u16* l) {
    __builtin_amdgcn_global_load_lds((const __attribute__((address_space(1))) unsigned int*)g,
                                     (__attribute__((address_space(3))) unsigned int*)l,
                                     16, 0, 0);
}

// ---------------- fused prep: cast x (packed u32x2 stores) + transpose w_qkv + w_proj --------
__global__ __launch_bounds__(256) void prep_kernel(const float* __restrict__ x,
                                                   const float* __restrict__ w_qkv,
                                                   const float* __restrict__ w_proj,
                                                   u16* __restrict__ x_bf,
                                                   u16* __restrict__ wqkv_t,
                                                   u16* __restrict__ wproj_t) {
    __shared__ float tile[64][65];
    int bid = blockIdx.x;
    int t = threadIdx.x;
    if (bid < 1024) {
        int base = bid * 4096 + t * 4;
#pragma unroll
        for (int it = 0; it < 4; ++it) {
            int i = base + it * 1024;
            float4 v = *(const float4*)(x + i);
            *(u32x2*)(x_bf + i) = (u32x2){pk2(v.x, v.y), pk2(v.z, v.w)};
        }
        return;
    }
    const float* in;
    u16* out;
    int N, tidx;
    if (bid < 1792) { in = w_qkv; out = wqkv_t; N = 3 * C_; tidx = bid - 1024; }
    else            { in = w_proj; out = wproj_t; N = C_;  tidx = bid - 1792; }
    int ntiles = N / 64;
    int n0 = (tidx % ntiles) * 64, k0 = (tidx / ntiles) * 64;
    int c = t & 63, r0 = t >> 6;
    for (int i = 0; i < 16; ++i) {
        int r = r0 * 16 + i;
        tile[r][c] = in[(size_t)(k0 + r) * N + n0 + c];
    }
    __syncthreads();
    for (int i = 0; i < 16; ++i) {
        int rn = r0 * 16 + i;
        out[(size_t)(n0 + rn) * C_ + k0 + c] = f2bf(tile[c][rn]);
    }
}

// ---------------- fused QKV GEMM, 8-phase 256x256 schedule (T3+T4+T2+T5) ----------------
// barrier -> stage -> vmcnt(2) -> BARRIER -> ds_read: every wave's tile-kt staging loads
// provably complete (vmcnt retired) before ANY wave's ds_read of tile kt. (race-free, R7;
// R9 measured the extra barrier at ~0 cost vs R5's racy variant)
__global__ __launch_bounds__(512, 2) void qkv_gemm(const u16* __restrict__ x_bf,
                                                   const u16* __restrict__ wqkv_t,
                                                   u16* __restrict__ Qo, u16* __restrict__ Ko,
                                                   u16* __restrict__ Vto) {
    __shared__ __align__(16) u16 smem[65536];  // As[2][256][64] = [0:32768], Bs = [32768:65536]
    const int K = 1024;
    int bid = blockIdx.x;
    bool qk = (bid < 128);
    const u16 *A, *Bt;
    int m0, n0;
    if (qk) {
        A = x_bf; Bt = wqkv_t;
        m0 = (bid >> 3) * 256; n0 = (bid & 7) * 256;
    } else {
        int vb = bid - 128;
        A = wqkv_t + 2048 * 1024; Bt = x_bf;
        m0 = (vb >> 4) * 256; n0 = (vb & 15) * 256;
    }
    int t = threadIdx.x;
    int wave = t >> 6, lane = t & 63, lr = lane & 15, quad = lane >> 4;
    int wave_m = wave >> 2, wave_n = wave & 3;
    int wm = wave_m * 128, wn = wave_n * 64;

    u16* As = smem;
    u16* Bs = smem + 32768;

    // staging: lane l -> row (l>>3) of its 8-row group, dest k-chunk (l&7)*8 (linear);
    // source k pre-swizzled by the (row&7) involution so swizzled ds_reads see the right data
    int gk = (((lane & 7) ^ ((lane >> 3) & 7))) * 8;
    int srow8 = wave * 8 + (lane >> 3);  // 0..63 within a 64-row staging group

    f32x4 acc[8][4];
#pragma unroll
    for (int i = 0; i < 8; ++i)
#pragma unroll
        for (int j = 0; j < 4; ++j) acc[i][j] = (f32x4){0.f, 0.f, 0.f, 0.f};

    auto stageA = [&](int buf, int kt, int h) {
#pragma unroll
        for (int j = 0; j < 2; ++j) {
            int row = h * 128 + j * 64 + srow8;
            gll16(&A[(size_t)(m0 + row) * K + kt * 64 + gk],
                  &As[buf * 16384 + (h * 128 + j * 64 + wave * 8) * 64]);
        }
    };
    auto stageB = [&](int buf, int kt, int h) {
#pragma unroll
        for (int j = 0; j < 2; ++j) {
            int row = h * 128 + j * 64 + srow8;
            gll16(&Bt[(size_t)(n0 + row) * K + kt * 64 + gk],
                  &Bs[buf * 16384 + (h * 128 + j * 64 + wave * 8) * 64]);
        }
    };

    bf16x8 aA[4][2], aB[4][2];
    int kswz = ((lr & 7) << 3);
    auto ldA = [&](int buf, int qm) {
        const u16* p = &As[buf * 16384 + (wm + qm * 64) * 64];
#pragma unroll
        for (int mt = 0; mt < 4; ++mt)
#pragma unroll
            for (int kh = 0; kh < 2; ++kh)
                aA[mt][kh] = *(const bf16x8*)&p[(mt * 16 + lr) * 64 + (((kh << 5) | (quad << 3)) ^ kswz)];
    };
    auto ldB = [&](int buf, int qn) {
        const u16* p = &Bs[buf * 16384 + (wn + qn * 32) * 64];
#pragma unroll
        for (int nt = 0; nt < 2; ++nt)
#pragma unroll
            for (int kh = 0; kh < 2; ++kh)
                aB[qn * 2 + nt][kh] = *(const bf16x8*)&p[(nt * 16 + lr) * 64 + (((kh << 5) | (quad << 3)) ^ kswz)];
    };
    auto mfmaQ = [&](int qm, int qn) {
        __builtin_amdgcn_s_setprio(1);
#pragma unroll
        for (int kh = 0; kh < 2; ++kh)
#pragma unroll
            for (int mt = 0; mt < 4; ++mt)
#pragma unroll
                for (int nt = 0; nt < 2; ++nt)
                    acc[qm * 4 + mt][qn * 2 + nt] =
                        mfma16(aA[mt][kh], aB[qn * 2 + nt][kh], acc[qm * 4 + mt][qn * 2 + nt]);
        __builtin_amdgcn_s_setprio(0);
    };

    // prologue: stage tile 0 (4 halves = 8 loads/thread)
    stageA(0, 0, 0); stageA(0, 0, 1); stageB(0, 0, 0); stageB(0, 0, 1);

    for (int kt = 0; kt < 16; ++kt) {
        int buf = kt & 1;
        bool pf = (kt < 15);
        // phase q0 (quadrant m-half0 x n-half0)
        __builtin_amdgcn_s_barrier();  // prev-iter reads of As/Bs[buf^1] all retired
        asm volatile("" ::: "memory");
        if (pf) stageA(buf ^ 1, kt + 1, 0);
        if (pf) asm volatile("s_waitcnt vmcnt(2)" ::: "memory");
        else    asm volatile("s_waitcnt vmcnt(0)" ::: "memory");
        __builtin_amdgcn_s_barrier();  // ALL waves' tile-kt staging complete before any read
        asm volatile("" ::: "memory");
        __builtin_amdgcn_sched_barrier(0);
        ldA(buf, 0); ldB(buf, 0);
        mfmaQ(0, 0);
        // phase q1 (m-half0 x n-half1)
        __builtin_amdgcn_s_barrier();
        asm volatile("" ::: "memory");
        if (pf) stageA(buf ^ 1, kt + 1, 1);
        ldB(buf, 1);
        mfmaQ(0, 1);
        // phase q2 (m-half1 x n-half1)
        __builtin_amdgcn_s_barrier();
        asm volatile("" ::: "memory");
        if (pf) stageB(buf ^ 1, kt + 1, 0);
        ldA(buf, 1);
        mfmaQ(1, 1);
        // phase q3 (m-half1 x n-half0) — aB[0..1] still live from q0
        __builtin_amdgcn_s_barrier();
        asm volatile("" ::: "memory");
        if (pf) stageB(buf ^ 1, kt + 1, 1);
        mfmaQ(1, 0);
    }

    __builtin_amdgcn_s_barrier();
    asm volatile("" ::: "memory");

    // coalesced transposed epilogue (r9/r10 pattern, p extended to 8 m-frags per wave)
    u16* eb = smem + wave * 1152;
    int row = lane >> 2;
    int cb = (lane & 3) * 16;
    if (qk) {
        int colg = n0 + wn;
        int part = colg >> 10;
        int h = (colg & 1023) >> 6;
        float sc = (part == 0) ? QSCALE : 1.0f;
        u16* outb = (part == 0) ? Qo : Ko;
#pragma unroll
        for (int p = 0; p < 8; ++p) {
            asm volatile("" ::: "memory");
#pragma unroll
            for (int nt = 0; nt < 4; ++nt)
#pragma unroll
                for (int r = 0; r < 4; ++r)
                    eb[(quad * 4 + r) * 72 + nt * 16 + lr] = f2bf(acc[p][nt][r] * sc);
            asm volatile("" ::: "memory");
            u16x8 va = *(const u16x8*)(eb + row * 72 + cb);
            u16x8 vb = *(const u16x8*)(eb + row * 72 + cb + 8);
            asm volatile("" ::: "memory");
            int rowg = m0 + wm + p * 16 + row;
            int bb = rowg >> 11, tt = rowg & 2047;
            int bh = bb * H_ + h;
            u32* dst = (u32*)(outb + ((size_t)(bh * T_ + tt)) * D_ + cb);
            *(u32x4*)dst = __builtin_bit_cast(u32x4, va);
            *(u32x4*)(dst + 4) = __builtin_bit_cast(u32x4, vb);
        }
    } else {
#pragma unroll
        for (int p = 0; p < 8; ++p) {
            asm volatile("" ::: "memory");
#pragma unroll
            for (int nt = 0; nt < 4; ++nt)
#pragma unroll
                for (int r = 0; r < 4; ++r)
                    eb[(quad * 4 + r) * 72 + nt * 16 + lr] = f2bf(acc[p][nt][r]);
            asm volatile("" ::: "memory");
            u16x8 va = *(const u16x8*)(eb + row * 72 + cb);
            u16x8 vb = *(const u16x8*)(eb + row * 72 + cb + 8);
            asm volatile("" ::: "memory");
            int rowg = m0 + wm + p * 16 + row;
            int h = rowg >> 6, d = rowg & 63;
            int tg = n0 + wn + cb;
            int bb = tg >> 11, tt = tg & 2047;
            u32* dst = (u32*)(Vto + (((size_t)(bb * H_ + h)) * D_ + d) * T_ + tt);
            *(u32x4*)dst = __builtin_bit_cast(u32x4, va);
            *(u32x4*)(dst + 4) = __builtin_bit_cast(u32x4, vb);
        }
    }
}

// ---------------- proj GEMM 128x128 with dbuf staging + conflict-free swizzle ----------------
__global__ __launch_bounds__(256) void gemm128_proj(const u16* __restrict__ A,
                                                    const u16* __restrict__ Bt,
                                                    float* __restrict__ Cout,
                                                    const float* __restrict__ bias,
                                                    int M, int N, int K) {
    __shared__ __align__(16) u16 smem[16384];  // As[2][128][32]=[0:8192], Bs[2][128][32]=[8192:16384]
    int m0 = blockIdx.y * 128, n0 = blockIdx.x * 128;
    int t = threadIdx.x;
    int wave = t >> 6, lane = t & 63, lr = lane & 15, quad = lane >> 4;
    int srow = lane >> 2;
    int sgl = (lane & 3) ^ ((srow >> 1) & 3);
    int swz = (quad ^ ((lr >> 1) & 3)) * 8;

    f32x4 acc[2][8];
#pragma unroll
    for (int i = 0; i < 2; ++i)
#pragma unroll
        for (int j = 0; j < 8; ++j) acc[i][j] = (f32x4){0.f, 0.f, 0.f, 0.f};

    auto stage = [&](int b, int kb) {
        u16* As = smem + b * 4096;
        u16* Bs = smem + 8192 + b * 4096;
#pragma unroll
        for (int i = 0; i < 2; ++i) {
            int c = wave * 2 + i;
            int row = c * 16 + srow;
            gll16(&A[(size_t)(m0 + row) * K + kb + sgl * 8], &As[c * 512]);
            gll16(&Bt[(size_t)(n0 + row) * K + kb + sgl * 8], &Bs[c * 512]);
        }
    };

    int niter = K / 32;
    stage(0, 0);
    for (int kt = 0; kt < niter; ++kt) {
        int buf = kt & 1;
        __syncthreads();
        if (kt < niter - 1) stage(buf ^ 1, (kt + 1) * 32);
        const u16* As = smem + buf * 4096;
        const u16* Bs = smem + 8192 + buf * 4096;
        bf16x8 af[2], bfr[8];
#pragma unroll
        for (int mt = 0; mt < 2; ++mt)
            af[mt] = *(const bf16x8*)&As[(wave * 32 + mt * 16 + lr) * 32 + swz];
#pragma unroll
        for (int nt = 0; nt < 8; ++nt)
            bfr[nt] = *(const bf16x8*)&Bs[(nt * 16 + lr) * 32 + swz];
#pragma unroll
        for (int mt = 0; mt < 2; ++mt)
#pragma unroll
            for (int nt = 0; nt < 8; ++nt) acc[mt][nt] = mfma16(af[mt], bfr[nt], acc[mt][nt]);
    }

#pragma unroll
    for (int mt = 0; mt < 2; ++mt)
#pragma unroll
        for (int nt = 0; nt < 8; ++nt)
#pragma unroll
            for (int r = 0; r < 4; ++r) {
                int rowg = m0 + wave * 32 + mt * 16 + quad * 4 + r;
                int col = n0 + nt * 16 + lr;
                Cout[(size_t)rowg * N + col] = acc[mt][nt][r] + bias[col];
            }
}

// ---------------- flash attention (r7 structure + setprio + b64 P/O stores) -------------------
// R12: single-variable vs R11 — the 8x ds_write_b32 P-exchange (and O-epilogue) merged into
// 4x u32x2 (ds_write_b64) stores. Alignment: index = lr*32 + (quad&1)*2 + ((..)<<2) is even
// -> 8B-aligned; rp=0,1 words contiguous. Isolates R0's unexplored suspect.
__global__ __launch_bounds__(256, 4) void attn_kernel(const u16* __restrict__ Q,
                                                      const u16* __restrict__ Kb,
                                                      const u16* __restrict__ Vt,
                                                      u16* __restrict__ Y) {
    __shared__ __align__(16) u16 Kls[2][64 * 64];
    __shared__ __align__(16) u16 Vls[2][64 * 64];
    __shared__ __align__(16) u32 Pls[4][512];
    int qt = 31 - (blockIdx.x >> 5);  // heavy-first
    int bh = blockIdx.x & 31;
    int t = threadIdx.x, wave = t >> 6, lane = t & 63, lr = lane & 15, quad = lane >> 4;

    const u16* kbase = Kb + (size_t)bh * (T_ * D_);
    const u16* vbase = Vt + (size_t)bh * (D_ * T_);
    const u16* Qg = Q + ((size_t)bh * T_ + qt * 64 + wave * 16 + lr) * D_;
    bf16x8 qfl = *(const bf16x8*)(Qg + quad * 8);
    bf16x8 qfh = *(const bf16x8*)(Qg + 32 + quad * 8);

    float lsum = 0.f;
    f32x4 o[4];
#pragma unroll
    for (int dt = 0; dt < 4; ++dt) o[dt] = (f32x4){0.f, 0.f, 0.f, 0.f};

    int srow = lane >> 3;
    int sgl = (lane & 7) ^ srow;
    int swz1 = (quad ^ (lr & 7)) * 8;
    int swz2 = ((quad + 4) ^ (lr & 7)) * 8;
    u32* pw = &Pls[wave][0];
    int pwbase = lr * 32 + (quad & 1) * 2;
    int rg1 = (quad ^ (lr & 7)) << 2;
    int rg2 = ((quad + 4) ^ (lr & 7)) << 2;

    for (int i = 0; i < 2; ++i) {
        int c = wave * 2 + i;
        int row = c * 8 + srow;
        gll16(kbase + (size_t)row * D_ + sgl * 8, &Kls[0][c * 512]);
        gll16(vbase + (size_t)row * T_ + sgl * 8, &Vls[0][c * 512]);
    }

    for (int kt = 0; kt <= qt; ++kt) {
        int buf = kt & 1;
        __syncthreads();
        if (kt < qt) {
            int nk = kt + 1;
            for (int i = 0; i < 2; ++i) {
                int c = wave * 2 + i;
                int row = c * 8 + srow;
                gll16(kbase + (size_t)(nk * 64 + row) * D_ + sgl * 8, &Kls[buf ^ 1][c * 512]);
                gll16(vbase + (size_t)row * T_ + nk * 64 + sgl * 8, &Vls[buf ^ 1][c * 512]);
            }
        }
        bf16x8 kf0[4], kf1[4], vf0[4], vf1[4];
#pragma unroll
        for (int st = 0; st < 4; ++st) {
            const u16* kp = &Kls[buf][(st * 16 + lr) * 64];
            kf0[st] = *(const bf16x8*)(kp + swz1);
            kf1[st] = *(const bf16x8*)(kp + swz2);
            const u16* vp = &Vls[buf][(st * 16 + lr) * 64];
            vf0[st] = *(const bf16x8*)(vp + swz1);
            vf1[st] = *(const bf16x8*)(vp + swz2);
        }
        f32x4 s[4];
        __builtin_amdgcn_s_setprio(1);
#pragma unroll
        for (int st = 0; st < 4; ++st) {
            s[st] = mfma16(kf0[st], qfl, (f32x4){0.f, 0.f, 0.f, 0.f});
            s[st] = mfma16(kf1[st], qfh, s[st]);
        }
        __builtin_amdgcn_s_setprio(0);
        if (kt == qt) {
            int qloc = wave * 16 + lr;
#pragma unroll
            for (int st = 0; st < 4; ++st)
#pragma unroll
                for (int r = 0; r < 4; ++r) {
                    if (st * 16 + quad * 4 + r > qloc) s[st][r] = -__builtin_inff();
                }
        }
        float sum = 0.f;
#pragma unroll
        for (int st = 0; st < 4; ++st)
#pragma unroll
            for (int r = 0; r < 4; ++r) {
                float p = __builtin_amdgcn_exp2f(s[st][r]);
                s[st][r] = p;
                sum += p;
            }
        sum += __shfl_xor(sum, 16);
        sum += __shfl_xor(sum, 32);
        lsum += sum;
        asm volatile("" ::: "memory");
#pragma unroll
        for (int st = 0; st < 4; ++st) {
            u32 w0 = pk2(s[st][0], s[st][1]);
            u32 w1 = pk2(s[st][2], s[st][3]);
            *(u32x2*)&pw[pwbase + (((st * 2 + (quad >> 1)) ^ (lr & 7)) << 2)] = (u32x2){w0, w1};
        }
        asm volatile("" ::: "memory");
        const u32* prow = &pw[lr * 32];
        u32x4 plo = *(const u32x4*)(prow + rg1);
        u32x4 phi = *(const u32x4*)(prow + rg2);
        asm volatile("" ::: "memory");
        bf16x8 pfl = __builtin_bit_cast(bf16x8, plo);
        bf16x8 pfh = __builtin_bit_cast(bf16x8, phi);
        __builtin_amdgcn_s_setprio(1);
#pragma unroll
        for (int dt = 0; dt < 4; ++dt) {
            o[dt] = mfma16(vf0[dt], pfl, o[dt]);
            o[dt] = mfma16(vf1[dt], pfh, o[dt]);
        }
        __builtin_amdgcn_s_setprio(0);
    }

    int b = bh >> 4, h = bh & 15;
    float inv = 1.0f / lsum;
    asm volatile("" ::: "memory");
#pragma unroll
    for (int dt = 0; dt < 4; ++dt) {
        u32 w0 = pk2(o[dt][0] * inv, o[dt][1] * inv);
        u32 w1 = pk2(o[dt][2] * inv, o[dt][3] * inv);
        *(u32x2*)&pw[pwbase + (((dt * 2 + (quad >> 1)) ^ (lr & 7)) << 2)] = (u32x2){w0, w1};
    }
    asm volatile("" ::: "memory");
    {
        int query = lane >> 2, wsel = lane & 3;
        const u32* prow = &pw[query * 32];
        u32x4 w0 = *(const u32x4*)(prow + (((wsel * 2) ^ (query & 7)) << 2));
        u32x4 w1 = *(const u32x4*)(prow + (((wsel * 2 + 1) ^ (query & 7)) << 2));
        u32* dst = (u32*)(Y + ((size_t)(b * T_ + qt * 64 + wave * 16 + query)) * C_ + h * 64 + wsel * 16);
        *(u32x4*)dst = w0;
        *(u32x4*)(dst + 4) = w1;
    }
}

extern "C" void kernel_launch(void* const* d_in, const int* in_sizes, int n_in,
                              void* d_out, int out_size, void* d_ws, size_t ws_size,
                              hipStream_t stream) {
    const float* x      = (const float*)d_in[0];
    const float* w_qkv  = (const float*)d_in[1];
    const float* w_proj = (const float*)d_in[2];
    const float* b_proj = (const float*)d_in[3];
    float* out = (float*)d_out;

    char* ws = (char*)d_ws;
    u16* x_bf    = (u16*)(ws + 0);          // 8 MB
    u16* wqkv_t  = (u16*)(ws + 8388608);    // 6 MB [n=3072][k=1024]
    u16* wproj_t = (u16*)(ws + 14680064);   // 2 MB
    u16* q_bf    = (u16*)(ws + 16777216);   // 8 MB  [bh][t][d] (pre-scaled)
    u16* k_bf    = (u16*)(ws + 25165824);   // 8 MB  [bh][t][d]
    u16* vt_bf   = (u16*)(ws + 33554432);   // 8 MB  [bh][d][t]
    u16* y_bf    = (u16*)(ws + 41943040);   // 8 MB  [b*t][c]

    const int M = B_ * T_;  // 4096

    // fused prep: cast + both weight transposes (2048 blocks)
    prep_kernel<<<2048, 256, 0, stream>>>(x, w_qkv, w_proj, x_bf, wqkv_t, wproj_t);

    // fused QKV: 8-phase 256x256 schedule, 192 blocks x 512 threads (race-free)
    qkv_gemm<<<192, 512, 0, stream>>>(x_bf, wqkv_t, q_bf, k_bf, vt_bf);

    // flash attention: 1024 4-wave blocks (dbuf V, b64 P/O stores), heavy-first
    attn_kernel<<<32 * (T_ / 64), 256, 0, stream>>>(q_bf, k_bf, vt_bf, y_bf);

    // proj gemm: [4096,1024] x [1024,1024]^T + bias (256 blocks, 128x128 tiles)
    gemm128_proj<<<dim3(C_ / 128, M / 128), 256, 0, stream>>>(
        y_bf, wproj_t, out, b_proj, M, C_, C_);
}

// Round 13
// 166.140 us; speedup vs baseline: 1.0133x; 1.0034x over previous
//
#include <hip/hip_runtime.h>

typedef __bf16 bf16x8 __attribute__((ext_vector_type(8)));
typedef float f32x4 __attribute__((ext_vector_type(4)));
typedef unsigned short u16;
typedef unsigned int u32;
typedef u32 u32x4 __attribute__((ext_vector_type(4)));
typedef u32 u32x2 __attribute__((ext_vector_type(2)));
typedef u16 u16x8 __attribute__((ext_vector_type(8)));

#define B_ 2
#define T_ 2048
#define C_ 1024
#define H_ 16
#define D_ 64
// 0.125 * log2(e): folded into Q so attn softmax runs in exp2 domain
#define QSCALE 0.18033688011112042f

// RNE f32->bf16 via the compiler's native path (m240: scalar cast is the fast path;
// pairs fuse to v_cvt_pk_bf16_f32).
__device__ __forceinline__ u16 f2bf(float f) {
    return __builtin_bit_cast(u16, (__bf16)f);
}

__device__ __forceinline__ u32 pk2(float a, float b) {
    return (u32)f2bf(a) | ((u32)f2bf(b) << 16);
}

__device__ __forceinline__ f32x4 mfma16(bf16x8 a, bf16x8 b, f32x4 c) {
    return __builtin_amdgcn_mfma_f32_16x16x32_bf16(a, b, c, 0, 0, 0);
}

// async global->LDS, 16B per lane; LDS dest = wave-uniform base + lane*16
__device__ __forceinline__ void gll16(const u16* g, u16* l) {
    __builtin_amdgcn_global_load_lds((const __attribute__((address_space(1))) unsigned int*)g,
                                     (__attribute__((address_space(3))) unsigned int*)l,
                                     16, 0, 0);
}

// ---------------- fused prep: cast x (packed u32x2 stores) + transpose w_qkv + w_proj --------
__global__ __launch_bounds__(256) void prep_kernel(const float* __restrict__ x,
                                                   const float* __restrict__ w_qkv,
                                                   const float* __restrict__ w_proj,
                                                   u16* __restrict__ x_bf,
                                                   u16* __restrict__ wqkv_t,
                                                   u16* __restrict__ wproj_t) {
    __shared__ float tile[64][65];
    int bid = blockIdx.x;
    int t = threadIdx.x;
    if (bid < 1024) {
        int base = bid * 4096 + t * 4;
#pragma unroll
        for (int it = 0; it < 4; ++it) {
            int i = base + it * 1024;
            float4 v = *(const float4*)(x + i);
            *(u32x2*)(x_bf + i) = (u32x2){pk2(v.x, v.y), pk2(v.z, v.w)};
        }
        return;
    }
    const float* in;
    u16* out;
    int N, tidx;
    if (bid < 1792) { in = w_qkv; out = wqkv_t; N = 3 * C_; tidx = bid - 1024; }
    else            { in = w_proj; out = wproj_t; N = C_;  tidx = bid - 1792; }
    int ntiles = N / 64;
    int n0 = (tidx % ntiles) * 64, k0 = (tidx / ntiles) * 64;
    int c = t & 63, r0 = t >> 6;
    for (int i = 0; i < 16; ++i) {
        int r = r0 * 16 + i;
        tile[r][c] = in[(size_t)(k0 + r) * N + n0 + c];
    }
    __syncthreads();
    for (int i = 0; i < 16; ++i) {
        int rn = r0 * 16 + i;
        out[(size_t)(n0 + rn) * C_ + k0 + c] = f2bf(tile[c][rn]);
    }
}

// ---------------- fused QKV GEMM, 8-phase 256x256 schedule (T3+T4+T2+T5) ----------------
// barrier -> stage -> vmcnt(2) -> BARRIER -> ds_read: every wave's tile-kt staging loads
// provably complete (vmcnt retired) before ANY wave's ds_read of tile kt. (race-free, R7;
// R9 measured the extra barrier at ~0 cost vs R5's racy variant)
__global__ __launch_bounds__(512, 2) void qkv_gemm(const u16* __restrict__ x_bf,
                                                   const u16* __restrict__ wqkv_t,
                                                   u16* __restrict__ Qo, u16* __restrict__ Ko,
                                                   u16* __restrict__ Vto) {
    __shared__ __align__(16) u16 smem[65536];  // As[2][256][64] = [0:32768], Bs = [32768:65536]
    const int K = 1024;
    int bid = blockIdx.x;
    bool qk = (bid < 128);
    const u16 *A, *Bt;
    int m0, n0;
    if (qk) {
        A = x_bf; Bt = wqkv_t;
        m0 = (bid >> 3) * 256; n0 = (bid & 7) * 256;
    } else {
        int vb = bid - 128;
        A = wqkv_t + 2048 * 1024; Bt = x_bf;
        m0 = (vb >> 4) * 256; n0 = (vb & 15) * 256;
    }
    int t = threadIdx.x;
    int wave = t >> 6, lane = t & 63, lr = lane & 15, quad = lane >> 4;
    int wave_m = wave >> 2, wave_n = wave & 3;
    int wm = wave_m * 128, wn = wave_n * 64;

    u16* As = smem;
    u16* Bs = smem + 32768;

    // staging: lane l -> row (l>>3) of its 8-row group, dest k-chunk (l&7)*8 (linear);
    // source k pre-swizzled by the (row&7) involution so swizzled ds_reads see the right data
    int gk = (((lane & 7) ^ ((lane >> 3) & 7))) * 8;
    int srow8 = wave * 8 + (lane >> 3);  // 0..63 within a 64-row staging group

    f32x4 acc[8][4];
#pragma unroll
    for (int i = 0; i < 8; ++i)
#pragma unroll
        for (int j = 0; j < 4; ++j) acc[i][j] = (f32x4){0.f, 0.f, 0.f, 0.f};

    auto stageA = [&](int buf, int kt, int h) {
#pragma unroll
        for (int j = 0; j < 2; ++j) {
            int row = h * 128 + j * 64 + srow8;
            gll16(&A[(size_t)(m0 + row) * K + kt * 64 + gk],
                  &As[buf * 16384 + (h * 128 + j * 64 + wave * 8) * 64]);
        }
    };
    auto stageB = [&](int buf, int kt, int h) {
#pragma unroll
        for (int j = 0; j < 2; ++j) {
            int row = h * 128 + j * 64 + srow8;
            gll16(&Bt[(size_t)(n0 + row) * K + kt * 64 + gk],
                  &Bs[buf * 16384 + (h * 128 + j * 64 + wave * 8) * 64]);
        }
    };

    bf16x8 aA[4][2], aB[4][2];
    int kswz = ((lr & 7) << 3);
    auto ldA = [&](int buf, int qm) {
        const u16* p = &As[buf * 16384 + (wm + qm * 64) * 64];
#pragma unroll
        for (int mt = 0; mt < 4; ++mt)
#pragma unroll
            for (int kh = 0; kh < 2; ++kh)
                aA[mt][kh] = *(const bf16x8*)&p[(mt * 16 + lr) * 64 + (((kh << 5) | (quad << 3)) ^ kswz)];
    };
    auto ldB = [&](int buf, int qn) {
        const u16* p = &Bs[buf * 16384 + (wn + qn * 32) * 64];
#pragma unroll
        for (int nt = 0; nt < 2; ++nt)
#pragma unroll
            for (int kh = 0; kh < 2; ++kh)
                aB[qn * 2 + nt][kh] = *(const bf16x8*)&p[(nt * 16 + lr) * 64 + (((kh << 5) | (quad << 3)) ^ kswz)];
    };
    auto mfmaQ = [&](int qm, int qn) {
        __builtin_amdgcn_s_setprio(1);
#pragma unroll
        for (int kh = 0; kh < 2; ++kh)
#pragma unroll
            for (int mt = 0; mt < 4; ++mt)
#pragma unroll
                for (int nt = 0; nt < 2; ++nt)
                    acc[qm * 4 + mt][qn * 2 + nt] =
                        mfma16(aA[mt][kh], aB[qn * 2 + nt][kh], acc[qm * 4 + mt][qn * 2 + nt]);
        __builtin_amdgcn_s_setprio(0);
    };

    // prologue: stage tile 0 (4 halves = 8 loads/thread)
    stageA(0, 0, 0); stageA(0, 0, 1); stageB(0, 0, 0); stageB(0, 0, 1);

    for (int kt = 0; kt < 16; ++kt) {
        int buf = kt & 1;
        bool pf = (kt < 15);
        // phase q0 (quadrant m-half0 x n-half0)
        __builtin_amdgcn_s_barrier();  // prev-iter reads of As/Bs[buf^1] all retired
        asm volatile("" ::: "memory");
        if (pf) stageA(buf ^ 1, kt + 1, 0);
        if (pf) asm volatile("s_waitcnt vmcnt(2)" ::: "memory");
        else    asm volatile("s_waitcnt vmcnt(0)" ::: "memory");
        __builtin_amdgcn_s_barrier();  // ALL waves' tile-kt staging complete before any read
        asm volatile("" ::: "memory");
        __builtin_amdgcn_sched_barrier(0);
        ldA(buf, 0); ldB(buf, 0);
        mfmaQ(0, 0);
        // phase q1 (m-half0 x n-half1)
        __builtin_amdgcn_s_barrier();
        asm volatile("" ::: "memory");
        if (pf) stageA(buf ^ 1, kt + 1, 1);
        ldB(buf, 1);
        mfmaQ(0, 1);
        // phase q2 (m-half1 x n-half1)
        __builtin_amdgcn_s_barrier();
        asm volatile("" ::: "memory");
        if (pf) stageB(buf ^ 1, kt + 1, 0);
        ldA(buf, 1);
        mfmaQ(1, 1);
        // phase q3 (m-half1 x n-half0) — aB[0..1] still live from q0
        __builtin_amdgcn_s_barrier();
        asm volatile("" ::: "memory");
        if (pf) stageB(buf ^ 1, kt + 1, 1);
        mfmaQ(1, 0);
    }

    __builtin_amdgcn_s_barrier();
    asm volatile("" ::: "memory");

    // coalesced transposed epilogue (r9/r10 pattern, p extended to 8 m-frags per wave)
    u16* eb = smem + wave * 1152;
    int row = lane >> 2;
    int cb = (lane & 3) * 16;
    if (qk) {
        int colg = n0 + wn;
        int part = colg >> 10;
        int h = (colg & 1023) >> 6;
        float sc = (part == 0) ? QSCALE : 1.0f;
        u16* outb = (part == 0) ? Qo : Ko;
#pragma unroll
        for (int p = 0; p < 8; ++p) {
            asm volatile("" ::: "memory");
#pragma unroll
            for (int nt = 0; nt < 4; ++nt)
#pragma unroll
                for (int r = 0; r < 4; ++r)
                    eb[(quad * 4 + r) * 72 + nt * 16 + lr] = f2bf(acc[p][nt][r] * sc);
            asm volatile("" ::: "memory");
            u16x8 va = *(const u16x8*)(eb + row * 72 + cb);
            u16x8 vb = *(const u16x8*)(eb + row * 72 + cb + 8);
            asm volatile("" ::: "memory");
            int rowg = m0 + wm + p * 16 + row;
            int bb = rowg >> 11, tt = rowg & 2047;
            int bh = bb * H_ + h;
            u32* dst = (u32*)(outb + ((size_t)(bh * T_ + tt)) * D_ + cb);
            *(u32x4*)dst = __builtin_bit_cast(u32x4, va);
            *(u32x4*)(dst + 4) = __builtin_bit_cast(u32x4, vb);
        }
    } else {
#pragma unroll
        for (int p = 0; p < 8; ++p) {
            asm volatile("" ::: "memory");
#pragma unroll
            for (int nt = 0; nt < 4; ++nt)
#pragma unroll
                for (int r = 0; r < 4; ++r)
                    eb[(quad * 4 + r) * 72 + nt * 16 + lr] = f2bf(acc[p][nt][r]);
            asm volatile("" ::: "memory");
            u16x8 va = *(const u16x8*)(eb + row * 72 + cb);
            u16x8 vb = *(const u16x8*)(eb + row * 72 + cb + 8);
            asm volatile("" ::: "memory");
            int rowg = m0 + wm + p * 16 + row;
            int h = rowg >> 6, d = rowg & 63;
            int tg = n0 + wn + cb;
            int bb = tg >> 11, tt = tg & 2047;
            u32* dst = (u32*)(Vto + (((size_t)(bb * H_ + h)) * D_ + d) * T_ + tt);
            *(u32x4*)dst = __builtin_bit_cast(u32x4, va);
            *(u32x4*)(dst + 4) = __builtin_bit_cast(u32x4, vb);
        }
    }
}

// ---------------- proj GEMM 128x128 with dbuf staging + conflict-free swizzle ----------------
__global__ __launch_bounds__(256) void gemm128_proj(const u16* __restrict__ A,
                                                    const u16* __restrict__ Bt,
                                                    float* __restrict__ Cout,
                                                    const float* __restrict__ bias,
                                                    int M, int N, int K) {
    __shared__ __align__(16) u16 smem[16384];  // As[2][128][32]=[0:8192], Bs[2][128][32]=[8192:16384]
    int m0 = blockIdx.y * 128, n0 = blockIdx.x * 128;
    int t = threadIdx.x;
    int wave = t >> 6, lane = t & 63, lr = lane & 15, quad = lane >> 4;
    int srow = lane >> 2;
    int sgl = (lane & 3) ^ ((srow >> 1) & 3);
    int swz = (quad ^ ((lr >> 1) & 3)) * 8;

    f32x4 acc[2][8];
#pragma unroll
    for (int i = 0; i < 2; ++i)
#pragma unroll
        for (int j = 0; j < 8; ++j) acc[i][j] = (f32x4){0.f, 0.f, 0.f, 0.f};

    auto stage = [&](int b, int kb) {
        u16* As = smem + b * 4096;
        u16* Bs = smem + 8192 + b * 4096;
#pragma unroll
        for (int i = 0; i < 2; ++i) {
            int c = wave * 2 + i;
            int row = c * 16 + srow;
            gll16(&A[(size_t)(m0 + row) * K + kb + sgl * 8], &As[c * 512]);
            gll16(&Bt[(size_t)(n0 + row) * K + kb + sgl * 8], &Bs[c * 512]);
        }
    };

    int niter = K / 32;
    stage(0, 0);
    for (int kt = 0; kt < niter; ++kt) {
        int buf = kt & 1;
        __syncthreads();
        if (kt < niter - 1) stage(buf ^ 1, (kt + 1) * 32);
        const u16* As = smem + buf * 4096;
        const u16* Bs = smem + 8192 + buf * 4096;
        bf16x8 af[2], bfr[8];
#pragma unroll
        for (int mt = 0; mt < 2; ++mt)
            af[mt] = *(const bf16x8*)&As[(wave * 32 + mt * 16 + lr) * 32 + swz];
#pragma unroll
        for (int nt = 0; nt < 8; ++nt)
            bfr[nt] = *(const bf16x8*)&Bs[(nt * 16 + lr) * 32 + swz];
#pragma unroll
        for (int mt = 0; mt < 2; ++mt)
#pragma unroll
            for (int nt = 0; nt < 8; ++nt) acc[mt][nt] = mfma16(af[mt], bfr[nt], acc[mt][nt]);
    }

#pragma unroll
    for (int mt = 0; mt < 2; ++mt)
#pragma unroll
        for (int nt = 0; nt < 8; ++nt)
#pragma unroll
            for (int r = 0; r < 4; ++r) {
                int rowg = m0 + wave * 32 + mt * 16 + quad * 4 + r;
                int col = n0 + nt * 16 + lr;
                Cout[(size_t)rowg * N + col] = acc[mt][nt][r] + bias[col];
            }
}

// ---------------- flash attention (r7 structure + setprio + b64 stores + deferred lsum) ------
// R13: single-variable vs R12 — the per-iteration 2-op __shfl_xor butterfly (ds_swizzle on
// the LDS pipe) is removed from the inner loop; each lane accumulates its per-lane partial
// exp-sum, and the butterfly runs ONCE after the loop. Associative reorder only (~1ulp f32).
__global__ __launch_bounds__(256, 4) void attn_kernel(const u16* __restrict__ Q,
                                                      const u16* __restrict__ Kb,
                                                      const u16* __restrict__ Vt,
                                                      u16* __restrict__ Y) {
    __shared__ __align__(16) u16 Kls[2][64 * 64];
    __shared__ __align__(16) u16 Vls[2][64 * 64];
    __shared__ __align__(16) u32 Pls[4][512];
    int qt = 31 - (blockIdx.x >> 5);  // heavy-first
    int bh = blockIdx.x & 31;
    int t = threadIdx.x, wave = t >> 6, lane = t & 63, lr = lane & 15, quad = lane >> 4;

    const u16* kbase = Kb + (size_t)bh * (T_ * D_);
    const u16* vbase = Vt + (size_t)bh * (D_ * T_);
    const u16* Qg = Q + ((size_t)bh * T_ + qt * 64 + wave * 16 + lr) * D_;
    bf16x8 qfl = *(const bf16x8*)(Qg + quad * 8);
    bf16x8 qfh = *(const bf16x8*)(Qg + 32 + quad * 8);

    float lsum = 0.f;  // per-lane partial (this lane's 16 k-slots per iteration)
    f32x4 o[4];
#pragma unroll
    for (int dt = 0; dt < 4; ++dt) o[dt] = (f32x4){0.f, 0.f, 0.f, 0.f};

    int srow = lane >> 3;
    int sgl = (lane & 7) ^ srow;
    int swz1 = (quad ^ (lr & 7)) * 8;
    int swz2 = ((quad + 4) ^ (lr & 7)) * 8;
    u32* pw = &Pls[wave][0];
    int pwbase = lr * 32 + (quad & 1) * 2;
    int rg1 = (quad ^ (lr & 7)) << 2;
    int rg2 = ((quad + 4) ^ (lr & 7)) << 2;

    for (int i = 0; i < 2; ++i) {
        int c = wave * 2 + i;
        int row = c * 8 + srow;
        gll16(kbase + (size_t)row * D_ + sgl * 8, &Kls[0][c * 512]);
        gll16(vbase + (size_t)row * T_ + sgl * 8, &Vls[0][c * 512]);
    }

    for (int kt = 0; kt <= qt; ++kt) {
        int buf = kt & 1;
        __syncthreads();
        if (kt < qt) {
            int nk = kt + 1;
            for (int i = 0; i < 2; ++i) {
                int c = wave * 2 + i;
                int row = c * 8 + srow;
                gll16(kbase + (size_t)(nk * 64 + row) * D_ + sgl * 8, &Kls[buf ^ 1][c * 512]);
                gll16(vbase + (size_t)row * T_ + nk * 64 + sgl * 8, &Vls[buf ^ 1][c * 512]);
            }
        }
        bf16x8 kf0[4], kf1[4], vf0[4], vf1[4];
#pragma unroll
        for (int st = 0; st < 4; ++st) {
            const u16* kp = &Kls[buf][(st * 16 + lr) * 64];
            kf0[st] = *(const bf16x8*)(kp + swz1);
            kf1[st] = *(const bf16x8*)(kp + swz2);
            const u16* vp = &Vls[buf][(st * 16 + lr) * 64];
            vf0[st] = *(const bf16x8*)(vp + swz1);
            vf1[st] = *(const bf16x8*)(vp + swz2);
        }
        f32x4 s[4];
        __builtin_amdgcn_s_setprio(1);
#pragma unroll
        for (int st = 0; st < 4; ++st) {
            s[st] = mfma16(kf0[st], qfl, (f32x4){0.f, 0.f, 0.f, 0.f});
            s[st] = mfma16(kf1[st], qfh, s[st]);
        }
        __builtin_amdgcn_s_setprio(0);
        if (kt == qt) {
            int qloc = wave * 16 + lr;
#pragma unroll
            for (int st = 0; st < 4; ++st)
#pragma unroll
                for (int r = 0; r < 4; ++r) {
                    if (st * 16 + quad * 4 + r > qloc) s[st][r] = -__builtin_inff();
                }
        }
#pragma unroll
        for (int st = 0; st < 4; ++st)
#pragma unroll
            for (int r = 0; r < 4; ++r) {
                float p = __builtin_amdgcn_exp2f(s[st][r]);
                s[st][r] = p;
                lsum += p;
            }
        asm volatile("" ::: "memory");
#pragma unroll
        for (int st = 0; st < 4; ++st) {
            u32 w0 = pk2(s[st][0], s[st][1]);
            u32 w1 = pk2(s[st][2], s[st][3]);
            *(u32x2*)&pw[pwbase + (((st * 2 + (quad >> 1)) ^ (lr & 7)) << 2)] = (u32x2){w0, w1};
        }
        asm volatile("" ::: "memory");
        const u32* prow = &pw[lr * 32];
        u32x4 plo = *(const u32x4*)(prow + rg1);
        u32x4 phi = *(const u32x4*)(prow + rg2);
        asm volatile("" ::: "memory");
        bf16x8 pfl = __builtin_bit_cast(bf16x8, plo);
        bf16x8 pfh = __builtin_bit_cast(bf16x8, phi);
        __builtin_amdgcn_s_setprio(1);
#pragma unroll
        for (int dt = 0; dt < 4; ++dt) {
            o[dt] = mfma16(vf0[dt], pfl, o[dt]);
            o[dt] = mfma16(vf1[dt], pfh, o[dt]);
        }
        __builtin_amdgcn_s_setprio(0);
    }

    // deferred butterfly: reduce the per-lane partials across the 4 quads, once
    lsum += __shfl_xor(lsum, 16);
    lsum += __shfl_xor(lsum, 32);

    int b = bh >> 4, h = bh & 15;
    float inv = 1.0f / lsum;
    asm volatile("" ::: "memory");
#pragma unroll
    for (int dt = 0; dt < 4; ++dt) {
        u32 w0 = pk2(o[dt][0] * inv, o[dt][1] * inv);
        u32 w1 = pk2(o[dt][2] * inv, o[dt][3] * inv);
        *(u32x2*)&pw[pwbase + (((dt * 2 + (quad >> 1)) ^ (lr & 7)) << 2)] = (u32x2){w0, w1};
    }
    asm volatile("" ::: "memory");
    {
        int query = lane >> 2, wsel = lane & 3;
        const u32* prow = &pw[query * 32];
        u32x4 w0 = *(const u32x4*)(prow + (((wsel * 2) ^ (query & 7)) << 2));
        u32x4 w1 = *(const u32x4*)(prow + (((wsel * 2 + 1) ^ (query & 7)) << 2));
        u32* dst = (u32*)(Y + ((size_t)(b * T_ + qt * 64 + wave * 16 + query)) * C_ + h * 64 + wsel * 16);
        *(u32x4*)dst = w0;
        *(u32x4*)(dst + 4) = w1;
    }
}

extern "C" void kernel_launch(void* const* d_in, const int* in_sizes, int n_in,
                              void* d_out, int out_size, void* d_ws, size_t ws_size,
                              hipStream_t stream) {
    const float* x      = (const float*)d_in[0];
    const float* w_qkv  = (const float*)d_in[1];
    const float* w_proj = (const float*)d_in[2];
    const float* b_proj = (const float*)d_in[3];
    float* out = (float*)d_out;

    char* ws = (char*)d_ws;
    u16* x_bf    = (u16*)(ws + 0);          // 8 MB
    u16* wqkv_t  = (u16*)(ws + 8388608);    // 6 MB [n=3072][k=1024]
    u16* wproj_t = (u16*)(ws + 14680064);   // 2 MB
    u16* q_bf    = (u16*)(ws + 16777216);   // 8 MB  [bh][t][d] (pre-scaled)
    u16* k_bf    = (u16*)(ws + 25165824);   // 8 MB  [bh][t][d]
    u16* vt_bf   = (u16*)(ws + 33554432);   // 8 MB  [bh][d][t]
    u16* y_bf    = (u16*)(ws + 41943040);   // 8 MB  [b*t][c]

    const int M = B_ * T_;  // 4096

    // fused prep: cast + both weight transposes (2048 blocks)
    prep_kernel<<<2048, 256, 0, stream>>>(x, w_qkv, w_proj, x_bf, wqkv_t, wproj_t);

    // fused QKV: 8-phase 256x256 schedule, 192 blocks x 512 threads (race-free)
    qkv_gemm<<<192, 512, 0, stream>>>(x_bf, wqkv_t, q_bf, k_bf, vt_bf);

    // flash attention: 1024 4-wave blocks (dbuf V, deferred lsum reduce), heavy-first
    attn_kernel<<<32 * (T_ / 64), 256, 0, stream>>>(q_bf, k_bf, vt_bf, y_bf);

    // proj gemm: [4096,1024] x [1024,1024]^T + bias (256 blocks, 128x128 tiles)
    gemm128_proj<<<dim3(C_ / 128, M / 128), 256, 0, stream>>>(
        y_bf, wproj_t, out, b_proj, M, C_, C_);
}